// Round 14
// baseline (173.085 us; speedup 1.0000x reference)
//
#include <hip/hip_runtime.h>
#include <hip/hip_bf16.h>
#include <math.h>

// Problem constants (SchNet reference)
#define NATOMS 16384
#define NMOL   512
#define APM    32
#define GDIM   50
#define KTAB   4096   // filter lookup-table knots over d in [0,6] (nearest-knot)
#define MAXEPM 1000   // max edges per molecule (992) + sentinel

#define STRH 132      // s_h row stride (floats), 528B
#define STRA 136      // s_agg / s_t row stride (ushorts), 272B

typedef __attribute__((ext_vector_type(8))) short   short8;   // 8 bf16 (A/B frag)
typedef __attribute__((ext_vector_type(4))) float   floatx4;  // C/D frag

// fast shifted softplus: log(1+exp(x)) - log2, via HW v_exp_f32/v_log_f32
__device__ __forceinline__ float ssp(float x) {
    float e = __expf(-fabsf(x));
    return fmaxf(x, 0.0f) + __logf(1.0f + e) - 0.69314718055994531f;
}

__device__ __forceinline__ unsigned short f2bf(float x) {
    union { float f; unsigned int u; } v; v.f = x;
    unsigned int lsb = (v.u >> 16) & 1u;
    v.u += 0x7fffu + lsb;
    return (unsigned short)(v.u >> 16);
}

__device__ __forceinline__ unsigned int pk2bf(float a, float b) {
    __hip_bfloat162 h = __float22bfloat162_rn(make_float2(a, b));
    unsigned int u;
    __builtin_memcpy(&u, &h, 4);
    return u;
}

// ---------------------------------------------------------------------------
// setup1 (element-wise, one pass over everything):
//  meta {knot<<6 | dst&31} (nearest knot), rowptr,
//  node weights -> bf16 B-frag [n][k] (9x128x128), out1^T (64x128),
//  mlp w1 -> w1T [l][128][64] (zero-padded g 50->64), w2 -> w2T [l][128][128]
// ---------------------------------------------------------------------------
__global__ __launch_bounds__(256) void setup1_kernel(
    const float* __restrict__ pos, const int* __restrict__ eidx, int E,
    int* __restrict__ rowptr,
    const float* __restrict__ cf1, const float* __restrict__ cf2,
    const float* __restrict__ lin, const float* __restrict__ out1,
    const float* __restrict__ w1_, const float* __restrict__ w2_,
    unsigned short* __restrict__ Wtall, unsigned int* __restrict__ meta,
    unsigned short* __restrict__ Wm1, unsigned short* __restrict__ Wm2)
{
    int idx = blockIdx.x * 256 + threadIdx.x;
    if (idx < E) {
        int s = eidx[idx], t = eidx[E + idx];
        float dx = pos[3 * s]     - pos[3 * t];
        float dy = pos[3 * s + 1] - pos[3 * t + 1];
        float dz = pos[3 * s + 2] - pos[3 * t + 2];
        float d  = sqrtf(dx * dx + dy * dy + dz * dz);
        float u  = d * (float)(KTAB - 1) / 6.0f;
        int i = min((int)(u + 0.5f), KTAB - 1);   // nearest knot
        meta[idx] = ((unsigned)i << 6) | (unsigned)(t & 31);
        return;
    }
    idx -= E;
    if (idx < NATOMS + 1) {
        int a = idx;
        int lo = 0, hi = E;
        while (lo < hi) { int mid = (lo + hi) >> 1; if (eidx[mid] < a) lo = mid + 1; else hi = mid; }
        rowptr[a] = lo;
        return;
    }
    idx -= NATOMS + 1;
    if (idx < 9 * 16384) {
        int wi = idx >> 14, rem = idx & 16383;
        int n = rem >> 7, k = rem & 127;
        int l = wi / 3, which = wi % 3;
        const float* src = (which == 0) ? cf1 : (which == 1) ? cf2 : lin;
        Wtall[idx] = f2bf(src[(size_t)l * 16384 + k * 128 + n]);
        return;
    }
    idx -= 9 * 16384;
    if (idx < 64 * 128) {
        int n = idx >> 7, k = idx & 127;
        Wtall[9 * 16384 + idx] = f2bf(out1[k * 64 + n]);
        return;
    }
    idx -= 64 * 128;
    if (idx < 3 * 128 * 64) {
        int l = idx / 8192, rem = idx % 8192;
        int n = rem >> 6, g = rem & 63;
        Wm1[idx] = (g < GDIM) ? f2bf(w1_[(size_t)l * GDIM * 128 + g * 128 + n]) : 0;
        return;
    }
    idx -= 3 * 128 * 64;
    if (idx < 3 * 128 * 128) {
        int l = idx / 16384, rem = idx % 16384;
        int n = rem >> 7, k = rem & 127;
        Wm2[idx] = f2bf(w2_[(size_t)l * 16384 + k * 128 + n]);
        return;
    }
}

// ---------------------------------------------------------------------------
// setup2: filter table. Block = (tile bx, layer l); B-frags straight from
// pre-transposed global (L2-hot); only the wave-private s_t LDS round trip.
//  T[l][k][f] = ((ssp(ea(d_k)@w1+b1)@w2)+b2)*cut(d_k), plain bf16.
// ---------------------------------------------------------------------------
#define KW2 136
#define NTILE (KTAB / 64)   // 64 tiles per layer

__global__ __launch_bounds__(256) void setup2_kernel(
    const unsigned short* __restrict__ Wm1, const unsigned short* __restrict__ Wm2,
    const float* __restrict__ b1_, const float* __restrict__ b2_,
    unsigned short* __restrict__ Tt)
{
    __shared__ unsigned short s_t[64 * KW2];   // 17.4 KB

    const int bx = blockIdx.x;
    const int l  = blockIdx.y;
    const unsigned short* W1m = Wm1 + (size_t)l * 128 * 64;
    const unsigned short* W2m = Wm2 + (size_t)l * 128 * 128;
    const float* b1 = b1_ + (size_t)l * 128;
    const float* b2 = b2_ + (size_t)l * 128;
    unsigned short* Tg = Tt + (size_t)l * KTAB * 128;

    const int tid  = threadIdx.x;
    const int lane = tid & 63;
    const int w    = tid >> 6;
    const int l15  = lane & 15;
    const int quad = lane >> 4;

    float b1v[8], b2v[8];
    #pragma unroll
    for (int nt = 0; nt < 8; nt++) {
        b1v[nt] = b1[nt * 16 + l15];
        b2v[nt] = b2[nt * 16 + l15];
    }

    const float hstep = 6.0f / (float)(KTAB - 1);
    const float step  = 6.0f / 49.0f;
    const float coeff = -0.5f / (step * step);
    const float pioc  = 3.14159265358979323846f / 6.0f;
    const int k0 = bx * 64;
    const float dm = (float)(k0 + w * 16 + l15) * hstep;

    // ---- MFMA1: t_pre = ea @ w1 (K=64 padded), B-frags from global ----
    floatx4 acc1[8];
    #pragma unroll
    for (int nt = 0; nt < 8; nt++) acc1[nt] = (floatx4){0.f, 0.f, 0.f, 0.f};
    #pragma unroll
    for (int ks = 0; ks < 2; ks++) {
        unsigned int ap[4];
        #pragma unroll
        for (int jj = 0; jj < 4; jj++) {
            int g0 = ks * 32 + quad * 8 + 2 * jj;
            float d0 = dm - (float)g0 * step;
            float d1 = dm - (float)(g0 + 1) * step;
            float v0 = (g0 < GDIM)     ? __expf(coeff * d0 * d0) : 0.0f;
            float v1 = (g0 + 1 < GDIM) ? __expf(coeff * d1 * d1) : 0.0f;
            ap[jj] = pk2bf(v0, v1);
        }
        short8 af;
        __builtin_memcpy(&af, ap, 16);
        #pragma unroll
        for (int nt = 0; nt < 8; nt++) {
            short8 bfg = *(const short8*)&W1m[(size_t)(nt * 16 + l15) * 64 + ks * 32 + quad * 8];
            acc1[nt] = __builtin_amdgcn_mfma_f32_16x16x32_bf16(af, bfg, acc1[nt], 0, 0, 0);
        }
    }
    #pragma unroll
    for (int nt = 0; nt < 8; nt++) {
        #pragma unroll
        for (int r = 0; r < 4; r++) {
            int row = w * 16 + quad * 4 + r;
            s_t[row * KW2 + nt * 16 + l15] = f2bf(ssp(acc1[nt][r] + b1v[nt]));
        }
    }
    // no barrier: wave reads only rows it wrote

    // ---- MFMA2: Wv = t @ w2 (K=128), B-frags from global ----
    floatx4 acc2[8];
    #pragma unroll
    for (int nt = 0; nt < 8; nt++) acc2[nt] = (floatx4){0.f, 0.f, 0.f, 0.f};
    #pragma unroll
    for (int ks = 0; ks < 4; ks++) {
        short8 af = *(const short8*)&s_t[(w * 16 + l15) * KW2 + ks * 32 + quad * 8];
        #pragma unroll
        for (int nt = 0; nt < 8; nt++) {
            short8 bfg = *(const short8*)&W2m[(size_t)(nt * 16 + l15) * 128 + ks * 32 + quad * 8];
            acc2[nt] = __builtin_amdgcn_mfma_f32_16x16x32_bf16(af, bfg, acc2[nt], 0, 0, 0);
        }
    }

    #pragma unroll
    for (int nt = 0; nt < 8; nt++) {
        #pragma unroll
        for (int r = 0; r < 4; r++) {
            int row = w * 16 + quad * 4 + r;
            float d = (float)(k0 + row) * hstep;
            float cut = 0.5f * (__cosf(d * pioc) + 1.0f);
            Tg[(size_t)(k0 + row) * 128 + nt * 16 + l15] = f2bf((acc2[nt][r] + b2v[nt]) * cut);
        }
    }
}

// ---------------------------------------------------------------------------
// Fully-fused SchNet (unchanged from R13, proven 72 us):
// one block = one molecule, 512 threads = 8 waves.
// GEMM tile per wave: rows (w&1)*16, cols (w>>1)*32.
// Gather: wave serially covers 4 atoms, lane = 2 channels, 8-deep unrolled,
// nearest-knot plain-bf16 table; sentinel edge -> zero hx row kills tails.
// ---------------------------------------------------------------------------
__global__ __launch_bounds__(512, 4) void fused_schnet_kernel(
    const int* __restrict__ z, const float* __restrict__ emb,
    const int* __restrict__ rowptr, const unsigned int* __restrict__ meta,
    const unsigned short* __restrict__ Tt,
    const unsigned short* __restrict__ Wtall,
    const float* __restrict__ cf2_b, const float* __restrict__ lin_b,
    const float* __restrict__ out1_b, const float* __restrict__ out2_w,
    const float* __restrict__ out2_b,
    float* __restrict__ out)
{
    __shared__ float s_h[32 * STRH];                 // 16.9 KB fp32 node state
    __shared__ float s_hx[33 * 128];                 // 16.9 KB; row 32 = zeros
    __shared__ unsigned short s_agg[32 * STRA];      //  8.7 KB bf16
    __shared__ unsigned int s_meta[MAXEPM];          //  4.0 KB
    __shared__ float s_red;
    unsigned short* s_t = (unsigned short*)s_hx;     // [32][STRA] alias (8.7KB)

    const int tid  = threadIdx.x;
    const int lane = tid & 63;
    const int w    = tid >> 6;          // wave 0..7
    const int l15  = lane & 15;
    const int quad = lane >> 4;
    const int r16  = (w & 1) * 16;      // GEMM row tile
    const int c32  = (w >> 1) * 32;     // GEMM col tile
    const int B0   = blockIdx.x * 32;   // molecule base atom

    // init h; zero hx dummy row
    for (int i = tid; i < 32 * 128; i += 512) {
        int row = i >> 7, col = i & 127;
        s_h[row * STRH + col] = emb[(size_t)z[B0 + row] * 128 + col];
    }
    if (tid < 128) s_hx[32 * 128 + tid] = 0.0f;
    if (tid == 0) s_red = 0.0f;

    // stage edge metadata + sentinel (knot 0, zero row 32)
    const int ebase = rowptr[B0];
    const int nE    = rowptr[B0 + 32] - ebase;
    for (int i = tid; i < nE; i += 512) s_meta[i] = meta[ebase + i];
    if (tid == 0) s_meta[nE] = 32u;

    // local row pointers for this wave's 4 atoms (5 bounds in lanes 0..4)
    const int rp = rowptr[B0 + w * 4 + min(lane, 4)] - ebase;

    const unsigned short* WtO = Wtall + 9 * 16384;   // out1^T

    for (int l = 0; l < 3; l++) {
        const unsigned short* W1 = Wtall + (size_t)(l * 3 + 0) * 16384;
        const unsigned short* W2 = Wtall + (size_t)(l * 3 + 1) * 16384;
        const unsigned short* W3 = Wtall + (size_t)(l * 3 + 2) * 16384;
        const unsigned short* Ttl = Tt + (size_t)l * KTAB * 128;

        __syncthreads();   // h ready (also covers init/meta staging at l=0)

        // ---- GEMM1: hx = h @ cf1 (16x32 tile per wave) ----
        floatx4 acc[2];
        #pragma unroll
        for (int nt = 0; nt < 2; nt++) acc[nt] = (floatx4){0.f, 0.f, 0.f, 0.f};
        #pragma unroll
        for (int ks = 0; ks < 4; ks++) {
            const float* hp = &s_h[(r16 + l15) * STRH + ks * 32 + quad * 8];
            float4 xa = *(const float4*)hp;
            float4 xb = *(const float4*)(hp + 4);
            unsigned int ap[4];
            ap[0] = pk2bf(xa.x, xa.y); ap[1] = pk2bf(xa.z, xa.w);
            ap[2] = pk2bf(xb.x, xb.y); ap[3] = pk2bf(xb.z, xb.w);
            short8 af;
            __builtin_memcpy(&af, ap, 16);
            #pragma unroll
            for (int nt = 0; nt < 2; nt++) {
                short8 bfg = *(const short8*)&W1[(size_t)(c32 + nt * 16 + l15) * 128 + ks * 32 + quad * 8];
                acc[nt] = __builtin_amdgcn_mfma_f32_16x16x32_bf16(af, bfg, acc[nt], 0, 0, 0);
            }
        }
        #pragma unroll
        for (int nt = 0; nt < 2; nt++) {
            #pragma unroll
            for (int r = 0; r < 4; r++)
                s_hx[(r16 + quad * 4 + r) * 128 + c32 + nt * 16 + l15] = acc[nt][r];
        }

        __syncthreads();   // hx complete before gather reads

        // ---- gather: wave per 4 atoms, 2 channels/lane, nearest-knot ----
        for (int al = 0; al < 4; al++) {
            const int e0 = __shfl(rp, al);
            const int e1 = __shfl(rp, al + 1);
            float ax[8], ay[8];
            #pragma unroll
            for (int j = 0; j < 8; j++) { ax[j] = 0.f; ay[j] = 0.f; }
            for (int e = e0; e < e1; e += 8) {
                #pragma unroll
                for (int j = 0; j < 8; j++) {
                    int idx = (e + j < e1) ? (e + j) : nE;   // sentinel
                    unsigned int q = s_meta[idx];
                    int tl   = q & 63;
                    int knot = q >> 6;
                    unsigned int tp = *(const unsigned int*)&Ttl[((size_t)knot << 7) + 2 * lane];
                    float2 hv = *(const float2*)&s_hx[(tl << 7) + 2 * lane];
                    ax[j] = fmaf(hv.x, __uint_as_float(tp << 16), ax[j]);
                    ay[j] = fmaf(hv.y, __uint_as_float(tp & 0xffff0000u), ay[j]);
                }
            }
            float sx = ((ax[0] + ax[1]) + (ax[2] + ax[3])) + ((ax[4] + ax[5]) + (ax[6] + ax[7]));
            float sy = ((ay[0] + ay[1]) + (ay[2] + ay[3])) + ((ay[4] + ay[5]) + (ay[6] + ay[7]));
            *(unsigned int*)&s_agg[(w * 4 + al) * STRA + 2 * lane] = pk2bf(sx, sy);
        }

        __syncthreads();   // agg complete; hx reads done (s_t alias safe)

        // ---- GEMM2: t = ssp(agg @ cf2 + b) ----
        float bva[2], bvb[2];
        #pragma unroll
        for (int nt = 0; nt < 2; nt++) {
            bva[nt] = cf2_b[l * 128 + c32 + nt * 16 + l15];
            bvb[nt] = lin_b[l * 128 + c32 + nt * 16 + l15];
        }
        #pragma unroll
        for (int nt = 0; nt < 2; nt++) acc[nt] = (floatx4){0.f, 0.f, 0.f, 0.f};
        #pragma unroll
        for (int ks = 0; ks < 4; ks++) {
            short8 af = *(const short8*)&s_agg[(r16 + l15) * STRA + ks * 32 + quad * 8];
            #pragma unroll
            for (int nt = 0; nt < 2; nt++) {
                short8 bfg = *(const short8*)&W2[(size_t)(c32 + nt * 16 + l15) * 128 + ks * 32 + quad * 8];
                acc[nt] = __builtin_amdgcn_mfma_f32_16x16x32_bf16(af, bfg, acc[nt], 0, 0, 0);
            }
        }
        #pragma unroll
        for (int nt = 0; nt < 2; nt++) {
            #pragma unroll
            for (int r = 0; r < 4; r++) {
                int row = r16 + quad * 4 + r;
                s_t[row * STRA + c32 + nt * 16 + l15] = f2bf(ssp(acc[nt][r] + bva[nt]));
            }
        }

        __syncthreads();   // t complete (cross-wave cols needed by GEMM3)

        // ---- GEMM3: h += t @ lin + b ----
        #pragma unroll
        for (int nt = 0; nt < 2; nt++) acc[nt] = (floatx4){0.f, 0.f, 0.f, 0.f};
        #pragma unroll
        for (int ks = 0; ks < 4; ks++) {
            short8 af = *(const short8*)&s_t[(r16 + l15) * STRA + ks * 32 + quad * 8];
            #pragma unroll
            for (int nt = 0; nt < 2; nt++) {
                short8 bfg = *(const short8*)&W3[(size_t)(c32 + nt * 16 + l15) * 128 + ks * 32 + quad * 8];
                acc[nt] = __builtin_amdgcn_mfma_f32_16x16x32_bf16(af, bfg, acc[nt], 0, 0, 0);
            }
        }
        #pragma unroll
        for (int nt = 0; nt < 2; nt++) {
            #pragma unroll
            for (int r = 0; r < 4; r++) {
                int row = r16 + quad * 4 + r;
                s_h[row * STRH + c32 + nt * 16 + l15] += acc[nt][r] + bvb[nt];
            }
        }
        // loop-top __syncthreads covers h
    }

    __syncthreads();

    // ---- head: out = sum_a ssp(h@out1 + b1)@out2 + 32*b2 ----
    const int c16 = (w >> 1) * 16;   // out1: 64 cols = 4 col tiles x 2 row tiles
    floatx4 ha = (floatx4){0.f, 0.f, 0.f, 0.f};
    #pragma unroll
    for (int ks = 0; ks < 4; ks++) {
        const float* hp = &s_h[(r16 + l15) * STRH + ks * 32 + quad * 8];
        float4 xa = *(const float4*)hp;
        float4 xb = *(const float4*)(hp + 4);
        unsigned int ap[4];
        ap[0] = pk2bf(xa.x, xa.y); ap[1] = pk2bf(xa.z, xa.w);
        ap[2] = pk2bf(xb.x, xb.y); ap[3] = pk2bf(xb.z, xb.w);
        short8 af;
        __builtin_memcpy(&af, ap, 16);
        short8 bfg = *(const short8*)&WtO[(size_t)(c16 + l15) * 128 + ks * 32 + quad * 8];
        ha = __builtin_amdgcn_mfma_f32_16x16x32_bf16(af, bfg, ha, 0, 0, 0);
    }
    float part = 0.0f;
    {
        float b1o = out1_b[c16 + l15];
        float o2  = out2_w[c16 + l15];
        #pragma unroll
        for (int r = 0; r < 4; r++)
            part += ssp(ha[r] + b1o) * o2;
    }
    #pragma unroll
    for (int off = 32; off > 0; off >>= 1) part += __shfl_down(part, off);
    if (lane == 0) atomicAdd(&s_red, part);
    __syncthreads();
    if (tid == 0) out[blockIdx.x] = s_red + 32.0f * out2_b[0];
}

extern "C" void kernel_launch(void* const* d_in, const int* in_sizes, int n_in,
                              void* d_out, int out_size, void* d_ws, size_t ws_size,
                              hipStream_t stream)
{
    const int*   z      = (const int*)d_in[0];
    const float* pos    = (const float*)d_in[1];
    const int*   eidx   = (const int*)d_in[3];
    const float* emb    = (const float*)d_in[4];
    const float* mlp_w1 = (const float*)d_in[5];
    const float* mlp_b1 = (const float*)d_in[6];
    const float* mlp_w2 = (const float*)d_in[7];
    const float* mlp_b2 = (const float*)d_in[8];
    const float* cf1_w  = (const float*)d_in[9];
    const float* cf2_w  = (const float*)d_in[10];
    const float* cf2_b  = (const float*)d_in[11];
    const float* lin_w  = (const float*)d_in[12];
    const float* lin_b  = (const float*)d_in[13];
    const float* out1_w = (const float*)d_in[14];
    const float* out1_b = (const float*)d_in[15];
    const float* out2_w = (const float*)d_in[16];
    const float* out2_b = (const float*)d_in[17];
    const int E = in_sizes[3] / 2;

    // workspace carve-up (16B-aligned sections)
    char* p = (char*)d_ws;
    unsigned int* meta = (unsigned int*)p;        p += ((size_t)(E + 1) * 4 + 63) & ~63ULL;
    unsigned short* Tt = (unsigned short*)p;      p += (size_t)3 * KTAB * 128 * 2;
    int* rowptr = (int*)p;                        p += ((size_t)(NATOMS + 1) * 4 + 63) & ~63ULL;
    unsigned short* Wtall = (unsigned short*)p;   p += (size_t)(9 * 16384 + 64 * 128) * 2;
    unsigned short* Wm1 = (unsigned short*)p;     p += (size_t)3 * 128 * 64 * 2;
    unsigned short* Wm2 = (unsigned short*)p;     // 3*128*128 ushorts

    const int total1 = E + (NATOMS + 1) + 9 * 16384 + 64 * 128
                     + 3 * 128 * 64 + 3 * 128 * 128;
    setup1_kernel<<<(total1 + 255) / 256, 256, 0, stream>>>(
        pos, eidx, E, rowptr, cf1_w, cf2_w, lin_w, out1_w,
        mlp_w1, mlp_w2, Wtall, meta, Wm1, Wm2);

    setup2_kernel<<<dim3(NTILE, 3), 256, 0, stream>>>(
        Wm1, Wm2, mlp_b1, mlp_b2, Tt);

    fused_schnet_kernel<<<NMOL, 512, 0, stream>>>(
        z, emb, rowptr, meta, Tt, Wtall,
        cf2_b, lin_b, out1_b, out2_w, out2_b, (float*)d_out);
}

// Round 15
// 171.310 us; speedup vs baseline: 1.0104x; 1.0104x over previous
//
#include <hip/hip_runtime.h>
#include <hip/hip_bf16.h>
#include <math.h>

// Problem constants (SchNet reference)
#define NATOMS 16384
#define NMOL   512
#define APM    32
#define GDIM   50
#define KTAB   4096   // filter lookup-table knots over d in [0,6] (nearest-knot)
#define MAXEPM 1000   // max edges per molecule (992) + sentinel

#define STRH 132      // s_h row stride (floats), 528B
#define STRA 136      // s_agg / s_t row stride (ushorts), 272B

typedef __attribute__((ext_vector_type(8))) short   short8;   // 8 bf16 (A/B frag)
typedef __attribute__((ext_vector_type(4))) float   floatx4;  // C/D frag

// fast shifted softplus: log(1+exp(x)) - log2, via HW v_exp_f32/v_log_f32
__device__ __forceinline__ float ssp(float x) {
    float e = __expf(-fabsf(x));
    return fmaxf(x, 0.0f) + __logf(1.0f + e) - 0.69314718055994531f;
}

__device__ __forceinline__ unsigned short f2bf(float x) {
    union { float f; unsigned int u; } v; v.f = x;
    unsigned int lsb = (v.u >> 16) & 1u;
    v.u += 0x7fffu + lsb;
    return (unsigned short)(v.u >> 16);
}

__device__ __forceinline__ unsigned int pk2bf(float a, float b) {
    __hip_bfloat162 h = __float22bfloat162_rn(make_float2(a, b));
    unsigned int u;
    __builtin_memcpy(&u, &h, 4);
    return u;
}

// ---------------------------------------------------------------------------
// MEGA-SETUP (single dispatch, 3 block regions):
//  [0,EB):        per-edge meta {knot<<6 | dst&31} (nearest knot) + rowptr
//  [EB,EB+WB):    weights fp32 -> bf16 B-frag transpose (9x128x128 + out1 64x128)
//  [EB+WB, +192): filter table, 64 tiles x 3 layers, plain bf16 rows:
//                 T[l][k][f] = ((ssp(ea(d_k)@w1+b1)@w2)+b2)*cut(d_k)
// ---------------------------------------------------------------------------
#define KW1 72
#define KW2 136
#define NTILE (KTAB / 64)   // 64 tiles per layer

__global__ __launch_bounds__(256) void mega_setup_kernel(
    const float* __restrict__ pos, const int* __restrict__ eidx, int E, int EB,
    int* __restrict__ rowptr,
    const float* __restrict__ cf1, const float* __restrict__ cf2,
    const float* __restrict__ lin, const float* __restrict__ out1,
    unsigned short* __restrict__ Wtall, unsigned int* __restrict__ meta,
    const float* __restrict__ w1_, const float* __restrict__ b1_,
    const float* __restrict__ w2_, const float* __restrict__ b2_,
    unsigned short* __restrict__ Tt)
{
    const int WB = (9 * 16384 + 64 * 128 + 255) / 256;
    const int b = blockIdx.x;
    const int tid = threadIdx.x;

    if (b < EB) {
        int idx = b * 256 + tid;
        if (idx < E) {
            int s = eidx[idx], t = eidx[E + idx];
            float dx = pos[3 * s]     - pos[3 * t];
            float dy = pos[3 * s + 1] - pos[3 * t + 1];
            float dz = pos[3 * s + 2] - pos[3 * t + 2];
            float d  = sqrtf(dx * dx + dy * dy + dz * dz);
            float u  = d * (float)(KTAB - 1) / 6.0f;
            int i = min((int)(u + 0.5f), KTAB - 1);   // nearest knot
            meta[idx] = ((unsigned)i << 6) | (unsigned)(t & 31);
        } else if (idx < E + NATOMS + 1) {
            int a = idx - E;
            int lo = 0, hi = E;
            while (lo < hi) { int mid = (lo + hi) >> 1; if (eidx[mid] < a) lo = mid + 1; else hi = mid; }
            rowptr[a] = lo;
        }
        return;
    }
    if (b < EB + WB) {
        int idx = (b - EB) * 256 + tid;
        if (idx < 9 * 16384) {
            int wi = idx >> 14, rem = idx & 16383;
            int n = rem >> 7, k = rem & 127;
            int l = wi / 3, which = wi % 3;
            const float* src = (which == 0) ? cf1 : (which == 1) ? cf2 : lin;
            Wtall[idx] = f2bf(src[(size_t)l * 16384 + k * 128 + n]);
        } else if (idx < 9 * 16384 + 64 * 128) {
            int q = idx - 9 * 16384;
            int n = q >> 7, k = q & 127;
            Wtall[idx] = f2bf(out1[k * 64 + n]);
        }
        return;
    }

    // ---------------- table region: tt = (layer, tile) ----------------
    __shared__ unsigned short s_bufA[128 * KW2];   // w2T
    __shared__ unsigned short s_bufB[128 * KW1];   // w1T, then s_t (alias)

    const int tt = b - EB - WB;
    const int l  = tt / NTILE;
    const int bx = tt % NTILE;
    const float* w1 = w1_ + (size_t)l * GDIM * 128;
    const float* b1 = b1_ + (size_t)l * 128;
    const float* w2 = w2_ + (size_t)l * 128 * 128;
    const float* b2 = b2_ + (size_t)l * 128;
    unsigned short* Tg = Tt + (size_t)l * KTAB * 128;

    unsigned short* s_w1T = s_bufB;                // [128][KW1]
    unsigned short* s_w2T = s_bufA;                // [128][KW2]
    unsigned short* s_t   = s_bufB;                // [64][KW2] (after barrier)

    for (int i = tid; i < GDIM * 128; i += 256) {
        int g = i >> 7, f = i & 127;
        s_w1T[f * KW1 + g] = f2bf(w1[i]);
    }
    for (int i = tid; i < (64 - GDIM) * 128; i += 256) {
        int g = GDIM + (i >> 7), f = i & 127;
        s_w1T[f * KW1 + g] = 0;
    }
    for (int i = tid; i < 128 * 128; i += 256) {
        int k = i >> 7, n = i & 127;
        s_w2T[n * KW2 + k] = f2bf(w2[i]);
    }

    const int lane = tid & 63;
    const int w    = tid >> 6;
    const int l15  = lane & 15;
    const int quad = lane >> 4;

    float b1v[8], b2v[8];
    #pragma unroll
    for (int nt = 0; nt < 8; nt++) {
        b1v[nt] = b1[nt * 16 + l15];
        b2v[nt] = b2[nt * 16 + l15];
    }
    __syncthreads();

    const float hstep = 6.0f / (float)(KTAB - 1);
    const float step  = 6.0f / 49.0f;
    const float coeff = -0.5f / (step * step);
    const float pioc  = 3.14159265358979323846f / 6.0f;
    const int k0 = bx * 64;
    const float dm = (float)(k0 + w * 16 + l15) * hstep;

    floatx4 acc1[8];
    #pragma unroll
    for (int nt = 0; nt < 8; nt++) acc1[nt] = (floatx4){0.f, 0.f, 0.f, 0.f};
    #pragma unroll
    for (int ks = 0; ks < 2; ks++) {
        unsigned int ap[4];
        #pragma unroll
        for (int jj = 0; jj < 4; jj++) {
            int g0 = ks * 32 + quad * 8 + 2 * jj;
            float d0 = dm - (float)g0 * step;
            float d1 = dm - (float)(g0 + 1) * step;
            float v0 = (g0 < GDIM)     ? __expf(coeff * d0 * d0) : 0.0f;
            float v1 = (g0 + 1 < GDIM) ? __expf(coeff * d1 * d1) : 0.0f;
            ap[jj] = pk2bf(v0, v1);
        }
        short8 af;
        __builtin_memcpy(&af, ap, 16);
        #pragma unroll
        for (int nt = 0; nt < 8; nt++) {
            short8 bfg = *(const short8*)&s_w1T[(nt * 16 + l15) * KW1 + ks * 32 + quad * 8];
            acc1[nt] = __builtin_amdgcn_mfma_f32_16x16x32_bf16(af, bfg, acc1[nt], 0, 0, 0);
        }
    }
    __syncthreads();   // all waves done reading s_w1T; s_t may alias it

    #pragma unroll
    for (int nt = 0; nt < 8; nt++) {
        #pragma unroll
        for (int r = 0; r < 4; r++) {
            int row = w * 16 + quad * 4 + r;
            s_t[row * KW2 + nt * 16 + l15] = f2bf(ssp(acc1[nt][r] + b1v[nt]));
        }
    }
    // no barrier: wave reads only rows it wrote

    floatx4 acc2[8];
    #pragma unroll
    for (int nt = 0; nt < 8; nt++) acc2[nt] = (floatx4){0.f, 0.f, 0.f, 0.f};
    #pragma unroll
    for (int ks = 0; ks < 4; ks++) {
        short8 af = *(const short8*)&s_t[(w * 16 + l15) * KW2 + ks * 32 + quad * 8];
        #pragma unroll
        for (int nt = 0; nt < 8; nt++) {
            short8 bfg = *(const short8*)&s_w2T[(nt * 16 + l15) * KW2 + ks * 32 + quad * 8];
            acc2[nt] = __builtin_amdgcn_mfma_f32_16x16x32_bf16(af, bfg, acc2[nt], 0, 0, 0);
        }
    }

    #pragma unroll
    for (int nt = 0; nt < 8; nt++) {
        #pragma unroll
        for (int r = 0; r < 4; r++) {
            int row = w * 16 + quad * 4 + r;
            float d = (float)(k0 + row) * hstep;
            float cut = 0.5f * (__cosf(d * pioc) + 1.0f);
            Tg[(size_t)(k0 + row) * 128 + nt * 16 + l15] = f2bf((acc2[nt][r] + b2v[nt]) * cut);
        }
    }
}

// ---------------------------------------------------------------------------
// Fully-fused SchNet: one block = one molecule, 512 threads = 8 waves.
// GEMM tile per wave: rows (w&1)*16, cols (w>>1)*32.
// Gather: wave covers 4 atoms as TWO INTERLEAVED PAIRS — atoms al/al+1 run
// concurrently with separate 8-deep accumulator sets (16 outstanding Tt
// loads per batch, serial batch-steps halved vs R13). Nearest-knot plain
// bf16 table; sentinel edge -> zero hx row kills loop tails.
// ---------------------------------------------------------------------------
__global__ __launch_bounds__(512, 4) void fused_schnet_kernel(
    const int* __restrict__ z, const float* __restrict__ emb,
    const int* __restrict__ rowptr, const unsigned int* __restrict__ meta,
    const unsigned short* __restrict__ Tt,
    const unsigned short* __restrict__ Wtall,
    const float* __restrict__ cf2_b, const float* __restrict__ lin_b,
    const float* __restrict__ out1_b, const float* __restrict__ out2_w,
    const float* __restrict__ out2_b,
    float* __restrict__ out)
{
    __shared__ float s_h[32 * STRH];                 // 16.9 KB fp32 node state
    __shared__ float s_hx[33 * 128];                 // 16.9 KB; row 32 = zeros
    __shared__ unsigned short s_agg[32 * STRA];      //  8.7 KB bf16
    __shared__ unsigned int s_meta[MAXEPM];          //  4.0 KB
    __shared__ float s_red;
    unsigned short* s_t = (unsigned short*)s_hx;     // [32][STRA] alias (8.7KB)

    const int tid  = threadIdx.x;
    const int lane = tid & 63;
    const int w    = tid >> 6;          // wave 0..7
    const int l15  = lane & 15;
    const int quad = lane >> 4;
    const int r16  = (w & 1) * 16;      // GEMM row tile
    const int c32  = (w >> 1) * 32;     // GEMM col tile
    const int B0   = blockIdx.x * 32;   // molecule base atom

    // init h; zero hx dummy row
    for (int i = tid; i < 32 * 128; i += 512) {
        int row = i >> 7, col = i & 127;
        s_h[row * STRH + col] = emb[(size_t)z[B0 + row] * 128 + col];
    }
    if (tid < 128) s_hx[32 * 128 + tid] = 0.0f;
    if (tid == 0) s_red = 0.0f;

    // stage edge metadata + sentinel (knot 0, zero row 32)
    const int ebase = rowptr[B0];
    const int nE    = rowptr[B0 + 32] - ebase;
    for (int i = tid; i < nE; i += 512) s_meta[i] = meta[ebase + i];
    if (tid == 0) s_meta[nE] = 32u;

    // local row pointers for this wave's 4 atoms (5 bounds in lanes 0..4)
    const int rp = rowptr[B0 + w * 4 + min(lane, 4)] - ebase;

    const unsigned short* WtO = Wtall + 9 * 16384;   // out1^T

    for (int l = 0; l < 3; l++) {
        const unsigned short* W1 = Wtall + (size_t)(l * 3 + 0) * 16384;
        const unsigned short* W2 = Wtall + (size_t)(l * 3 + 1) * 16384;
        const unsigned short* W3 = Wtall + (size_t)(l * 3 + 2) * 16384;
        const unsigned short* Ttl = Tt + (size_t)l * KTAB * 128;

        __syncthreads();   // h ready (also covers init/meta staging at l=0)

        // ---- GEMM1: hx = h @ cf1 (16x32 tile per wave) ----
        floatx4 acc[2];
        #pragma unroll
        for (int nt = 0; nt < 2; nt++) acc[nt] = (floatx4){0.f, 0.f, 0.f, 0.f};
        #pragma unroll
        for (int ks = 0; ks < 4; ks++) {
            const float* hp = &s_h[(r16 + l15) * STRH + ks * 32 + quad * 8];
            float4 xa = *(const float4*)hp;
            float4 xb = *(const float4*)(hp + 4);
            unsigned int ap[4];
            ap[0] = pk2bf(xa.x, xa.y); ap[1] = pk2bf(xa.z, xa.w);
            ap[2] = pk2bf(xb.x, xb.y); ap[3] = pk2bf(xb.z, xb.w);
            short8 af;
            __builtin_memcpy(&af, ap, 16);
            #pragma unroll
            for (int nt = 0; nt < 2; nt++) {
                short8 bfg = *(const short8*)&W1[(size_t)(c32 + nt * 16 + l15) * 128 + ks * 32 + quad * 8];
                acc[nt] = __builtin_amdgcn_mfma_f32_16x16x32_bf16(af, bfg, acc[nt], 0, 0, 0);
            }
        }
        #pragma unroll
        for (int nt = 0; nt < 2; nt++) {
            #pragma unroll
            for (int r = 0; r < 4; r++)
                s_hx[(r16 + quad * 4 + r) * 128 + c32 + nt * 16 + l15] = acc[nt][r];
        }

        __syncthreads();   // hx complete before gather reads

        // ---- gather: 2 atom-pairs, each pair interleaved 8-deep ----
        #pragma unroll
        for (int al = 0; al < 4; al += 2) {
            const int e0A = __shfl(rp, al);
            const int e1A = __shfl(rp, al + 1);
            const int e1B = __shfl(rp, al + 2);   // pair B = atom al+1
            float axA[8], ayA[8], axB[8], ayB[8];
            #pragma unroll
            for (int j = 0; j < 8; j++) { axA[j] = ayA[j] = axB[j] = ayB[j] = 0.f; }
            int eA = e0A, eB = e1A;
            const int nbat = (max(e1A - e0A, e1B - e1A) + 7) >> 3;
            for (int bt = 0; bt < nbat; bt++) {
                #pragma unroll
                for (int j = 0; j < 8; j++) {
                    int iA = (eA + j < e1A) ? (eA + j) : nE;
                    int iB = (eB + j < e1B) ? (eB + j) : nE;
                    unsigned int qA = s_meta[iA];
                    unsigned int qB = s_meta[iB];
                    unsigned int tpA = *(const unsigned int*)&Ttl[((size_t)(qA >> 6) << 7) + 2 * lane];
                    unsigned int tpB = *(const unsigned int*)&Ttl[((size_t)(qB >> 6) << 7) + 2 * lane];
                    float2 hvA = *(const float2*)&s_hx[((qA & 63) << 7) + 2 * lane];
                    float2 hvB = *(const float2*)&s_hx[((qB & 63) << 7) + 2 * lane];
                    axA[j] = fmaf(hvA.x, __uint_as_float(tpA << 16), axA[j]);
                    ayA[j] = fmaf(hvA.y, __uint_as_float(tpA & 0xffff0000u), ayA[j]);
                    axB[j] = fmaf(hvB.x, __uint_as_float(tpB << 16), axB[j]);
                    ayB[j] = fmaf(hvB.y, __uint_as_float(tpB & 0xffff0000u), ayB[j]);
                }
                eA += 8; eB += 8;
            }
            float sxA = ((axA[0] + axA[1]) + (axA[2] + axA[3])) + ((axA[4] + axA[5]) + (axA[6] + axA[7]));
            float syA = ((ayA[0] + ayA[1]) + (ayA[2] + ayA[3])) + ((ayA[4] + ayA[5]) + (ayA[6] + ayA[7]));
            float sxB = ((axB[0] + axB[1]) + (axB[2] + axB[3])) + ((axB[4] + axB[5]) + (axB[6] + axB[7]));
            float syB = ((ayB[0] + ayB[1]) + (ayB[2] + ayB[3])) + ((ayB[4] + ayB[5]) + (ayB[6] + ayB[7]));
            *(unsigned int*)&s_agg[(w * 4 + al) * STRA + 2 * lane]     = pk2bf(sxA, syA);
            *(unsigned int*)&s_agg[(w * 4 + al + 1) * STRA + 2 * lane] = pk2bf(sxB, syB);
        }

        __syncthreads();   // agg complete; hx reads done (s_t alias safe)

        // ---- GEMM2: t = ssp(agg @ cf2 + b) ----
        float bva[2], bvb[2];
        #pragma unroll
        for (int nt = 0; nt < 2; nt++) {
            bva[nt] = cf2_b[l * 128 + c32 + nt * 16 + l15];
            bvb[nt] = lin_b[l * 128 + c32 + nt * 16 + l15];
        }
        #pragma unroll
        for (int nt = 0; nt < 2; nt++) acc[nt] = (floatx4){0.f, 0.f, 0.f, 0.f};
        #pragma unroll
        for (int ks = 0; ks < 4; ks++) {
            short8 af = *(const short8*)&s_agg[(r16 + l15) * STRA + ks * 32 + quad * 8];
            #pragma unroll
            for (int nt = 0; nt < 2; nt++) {
                short8 bfg = *(const short8*)&W2[(size_t)(c32 + nt * 16 + l15) * 128 + ks * 32 + quad * 8];
                acc[nt] = __builtin_amdgcn_mfma_f32_16x16x32_bf16(af, bfg, acc[nt], 0, 0, 0);
            }
        }
        #pragma unroll
        for (int nt = 0; nt < 2; nt++) {
            #pragma unroll
            for (int r = 0; r < 4; r++) {
                int row = r16 + quad * 4 + r;
                s_t[row * STRA + c32 + nt * 16 + l15] = f2bf(ssp(acc[nt][r] + bva[nt]));
            }
        }

        __syncthreads();   // t complete (cross-wave cols needed by GEMM3)

        // ---- GEMM3: h += t @ lin + b ----
        #pragma unroll
        for (int nt = 0; nt < 2; nt++) acc[nt] = (floatx4){0.f, 0.f, 0.f, 0.f};
        #pragma unroll
        for (int ks = 0; ks < 4; ks++) {
            short8 af = *(const short8*)&s_t[(r16 + l15) * STRA + ks * 32 + quad * 8];
            #pragma unroll
            for (int nt = 0; nt < 2; nt++) {
                short8 bfg = *(const short8*)&W3[(size_t)(c32 + nt * 16 + l15) * 128 + ks * 32 + quad * 8];
                acc[nt] = __builtin_amdgcn_mfma_f32_16x16x32_bf16(af, bfg, acc[nt], 0, 0, 0);
            }
        }
        #pragma unroll
        for (int nt = 0; nt < 2; nt++) {
            #pragma unroll
            for (int r = 0; r < 4; r++) {
                int row = r16 + quad * 4 + r;
                s_h[row * STRH + c32 + nt * 16 + l15] += acc[nt][r] + bvb[nt];
            }
        }
        // loop-top __syncthreads covers h
    }

    __syncthreads();

    // ---- head: out = sum_a ssp(h@out1 + b1)@out2 + 32*b2 ----
    const int c16 = (w >> 1) * 16;   // out1: 64 cols = 4 col tiles x 2 row tiles
    floatx4 ha = (floatx4){0.f, 0.f, 0.f, 0.f};
    #pragma unroll
    for (int ks = 0; ks < 4; ks++) {
        const float* hp = &s_h[(r16 + l15) * STRH + ks * 32 + quad * 8];
        float4 xa = *(const float4*)hp;
        float4 xb = *(const float4*)(hp + 4);
        unsigned int ap[4];
        ap[0] = pk2bf(xa.x, xa.y); ap[1] = pk2bf(xa.z, xa.w);
        ap[2] = pk2bf(xb.x, xb.y); ap[3] = pk2bf(xb.z, xb.w);
        short8 af;
        __builtin_memcpy(&af, ap, 16);
        short8 bfg = *(const short8*)&WtO[(size_t)(c16 + l15) * 128 + ks * 32 + quad * 8];
        ha = __builtin_amdgcn_mfma_f32_16x16x32_bf16(af, bfg, ha, 0, 0, 0);
    }
    float part = 0.0f;
    {
        float b1o = out1_b[c16 + l15];
        float o2  = out2_w[c16 + l15];
        #pragma unroll
        for (int r = 0; r < 4; r++)
            part += ssp(ha[r] + b1o) * o2;
    }
    #pragma unroll
    for (int off = 32; off > 0; off >>= 1) part += __shfl_down(part, off);
    if (lane == 0) atomicAdd(&s_red, part);
    __syncthreads();
    if (tid == 0) out[blockIdx.x] = s_red + 32.0f * out2_b[0];
}

extern "C" void kernel_launch(void* const* d_in, const int* in_sizes, int n_in,
                              void* d_out, int out_size, void* d_ws, size_t ws_size,
                              hipStream_t stream)
{
    const int*   z      = (const int*)d_in[0];
    const float* pos    = (const float*)d_in[1];
    const int*   eidx   = (const int*)d_in[3];
    const float* emb    = (const float*)d_in[4];
    const float* mlp_w1 = (const float*)d_in[5];
    const float* mlp_b1 = (const float*)d_in[6];
    const float* mlp_w2 = (const float*)d_in[7];
    const float* mlp_b2 = (const float*)d_in[8];
    const float* cf1_w  = (const float*)d_in[9];
    const float* cf2_w  = (const float*)d_in[10];
    const float* cf2_b  = (const float*)d_in[11];
    const float* lin_w  = (const float*)d_in[12];
    const float* lin_b  = (const float*)d_in[13];
    const float* out1_w = (const float*)d_in[14];
    const float* out1_b = (const float*)d_in[15];
    const float* out2_w = (const float*)d_in[16];
    const float* out2_b = (const float*)d_in[17];
    const int E = in_sizes[3] / 2;

    // workspace carve-up (16B-aligned sections)
    char* p = (char*)d_ws;
    unsigned int* meta = (unsigned int*)p;        p += ((size_t)(E + 1) * 4 + 63) & ~63ULL;
    unsigned short* Tt = (unsigned short*)p;      p += (size_t)3 * KTAB * 128 * 2;
    int* rowptr = (int*)p;                        p += ((size_t)(NATOMS + 1) * 4 + 63) & ~63ULL;
    unsigned short* Wtall = (unsigned short*)p;   // 9*16384 + 64*128 ushorts

    const int EB = (E + NATOMS + 1 + 255) / 256;
    const int WB = (9 * 16384 + 64 * 128 + 255) / 256;
    const int TB = NTILE * 3;
    mega_setup_kernel<<<EB + WB + TB, 256, 0, stream>>>(
        pos, eidx, E, EB, rowptr, cf1_w, cf2_w, lin_w, out1_w, Wtall, meta,
        mlp_w1, mlp_b1, mlp_w2, mlp_b2, Tt);

    fused_schnet_kernel<<<NMOL, 512, 0, stream>>>(
        z, emb, rowptr, meta, Tt, Wtall,
        cf2_b, lin_b, out1_b, out2_w, out2_b, (float*)d_out);
}

// Round 17
// 169.197 us; speedup vs baseline: 1.0230x; 1.0125x over previous
//
#include <hip/hip_runtime.h>
#include <hip/hip_bf16.h>
#include <math.h>

// Problem constants (SchNet reference)
#define NATOMS 16384
#define NMOL   512
#define APM    32
#define GDIM   50
#define KTAB   4096   // filter lookup-table knots over d in [0,6] (nearest-knot)
#define MAXEPM 1000   // max edges per molecule (992) + sentinel

#define STRH 132      // s_h row stride (floats), 528B
#define STRA 136      // s_agg / s_t row stride (ushorts), 272B

typedef __attribute__((ext_vector_type(8))) short   short8;   // 8 bf16 (A/B frag)
typedef __attribute__((ext_vector_type(4))) float   floatx4;  // C/D frag

// fast shifted softplus: log(1+exp(x)) - log2, via HW v_exp_f32/v_log_f32
__device__ __forceinline__ float ssp(float x) {
    float e = __expf(-fabsf(x));
    return fmaxf(x, 0.0f) + __logf(1.0f + e) - 0.69314718055994531f;
}

__device__ __forceinline__ unsigned short f2bf(float x) {
    union { float f; unsigned int u; } v; v.f = x;
    unsigned int lsb = (v.u >> 16) & 1u;
    v.u += 0x7fffu + lsb;
    return (unsigned short)(v.u >> 16);
}

__device__ __forceinline__ unsigned int pk2bf(float a, float b) {
    __hip_bfloat162 h = __float22bfloat162_rn(make_float2(a, b));
    unsigned int u;
    __builtin_memcpy(&u, &h, 4);
    return u;
}

// ---------------------------------------------------------------------------
// MEGA-SETUP (single dispatch, 3 block regions):
//  [0,EB):        per-edge meta {knot<<6 | dst&31} (nearest knot) + rowptr
//  [EB,EB+WB):    weights fp32 -> bf16 B-frag transpose (9x128x128 + out1 64x128)
//  [EB+WB, +192): filter table, 64 tiles x 3 layers, plain bf16 rows:
//                 T[l][k][f] = ((ssp(ea(d_k)@w1+b1)@w2)+b2)*cut(d_k)
// ---------------------------------------------------------------------------
#define KW1 72
#define KW2 136
#define NTILE (KTAB / 64)   // 64 tiles per layer

__global__ __launch_bounds__(256) void mega_setup_kernel(
    const float* __restrict__ pos, const int* __restrict__ eidx, int E, int EB,
    int* __restrict__ rowptr,
    const float* __restrict__ cf1, const float* __restrict__ cf2,
    const float* __restrict__ lin, const float* __restrict__ out1,
    unsigned short* __restrict__ Wtall, unsigned int* __restrict__ meta,
    const float* __restrict__ w1_, const float* __restrict__ b1_,
    const float* __restrict__ w2_, const float* __restrict__ b2_,
    unsigned short* __restrict__ Tt)
{
    const int WB = (9 * 16384 + 64 * 128 + 255) / 256;
    const int b = blockIdx.x;
    const int tid = threadIdx.x;

    if (b < EB) {
        int idx = b * 256 + tid;
        if (idx < E) {
            int s = eidx[idx], t = eidx[E + idx];
            float dx = pos[3 * s]     - pos[3 * t];
            float dy = pos[3 * s + 1] - pos[3 * t + 1];
            float dz = pos[3 * s + 2] - pos[3 * t + 2];
            float d  = sqrtf(dx * dx + dy * dy + dz * dz);
            float u  = d * (float)(KTAB - 1) / 6.0f;
            int i = min((int)(u + 0.5f), KTAB - 1);   // nearest knot
            meta[idx] = ((unsigned)i << 6) | (unsigned)(t & 31);
        } else if (idx < E + NATOMS + 1) {
            int a = idx - E;
            int lo = 0, hi = E;
            while (lo < hi) { int mid = (lo + hi) >> 1; if (eidx[mid] < a) lo = mid + 1; else hi = mid; }
            rowptr[a] = lo;
        }
        return;
    }
    if (b < EB + WB) {
        int idx = (b - EB) * 256 + tid;
        if (idx < 9 * 16384) {
            int wi = idx >> 14, rem = idx & 16383;
            int n = rem >> 7, k = rem & 127;
            int l = wi / 3, which = wi % 3;
            const float* src = (which == 0) ? cf1 : (which == 1) ? cf2 : lin;
            Wtall[idx] = f2bf(src[(size_t)l * 16384 + k * 128 + n]);
        } else if (idx < 9 * 16384 + 64 * 128) {
            int q = idx - 9 * 16384;
            int n = q >> 7, k = q & 127;
            Wtall[idx] = f2bf(out1[k * 64 + n]);
        }
        return;
    }

    // ---------------- table region: tt = (layer, tile) ----------------
    __shared__ unsigned short s_bufA[128 * KW2];   // w2T
    __shared__ unsigned short s_bufB[128 * KW1];   // w1T, then s_t (alias)

    const int tt = b - EB - WB;
    const int l  = tt / NTILE;
    const int bx = tt % NTILE;
    const float* w1 = w1_ + (size_t)l * GDIM * 128;
    const float* b1 = b1_ + (size_t)l * 128;
    const float* w2 = w2_ + (size_t)l * 128 * 128;
    const float* b2 = b2_ + (size_t)l * 128;
    unsigned short* Tg = Tt + (size_t)l * KTAB * 128;

    unsigned short* s_w1T = s_bufB;                // [128][KW1]
    unsigned short* s_w2T = s_bufA;                // [128][KW2]
    unsigned short* s_t   = s_bufB;                // [64][KW2] (after barrier)

    for (int i = tid; i < GDIM * 128; i += 256) {
        int g = i >> 7, f = i & 127;
        s_w1T[f * KW1 + g] = f2bf(w1[i]);
    }
    for (int i = tid; i < (64 - GDIM) * 128; i += 256) {
        int g = GDIM + (i >> 7), f = i & 127;
        s_w1T[f * KW1 + g] = 0;
    }
    for (int i = tid; i < 128 * 128; i += 256) {
        int k = i >> 7, n = i & 127;
        s_w2T[n * KW2 + k] = f2bf(w2[i]);
    }

    const int lane = tid & 63;
    const int w    = tid >> 6;
    const int l15  = lane & 15;
    const int quad = lane >> 4;

    float b1v[8], b2v[8];
    #pragma unroll
    for (int nt = 0; nt < 8; nt++) {
        b1v[nt] = b1[nt * 16 + l15];
        b2v[nt] = b2[nt * 16 + l15];
    }
    __syncthreads();

    const float hstep = 6.0f / (float)(KTAB - 1);
    const float step  = 6.0f / 49.0f;
    const float coeff = -0.5f / (step * step);
    const float pioc  = 3.14159265358979323846f / 6.0f;
    const int k0 = bx * 64;
    const float dm = (float)(k0 + w * 16 + l15) * hstep;

    floatx4 acc1[8];
    #pragma unroll
    for (int nt = 0; nt < 8; nt++) acc1[nt] = (floatx4){0.f, 0.f, 0.f, 0.f};
    #pragma unroll
    for (int ks = 0; ks < 2; ks++) {
        unsigned int ap[4];
        #pragma unroll
        for (int jj = 0; jj < 4; jj++) {
            int g0 = ks * 32 + quad * 8 + 2 * jj;
            float d0 = dm - (float)g0 * step;
            float d1 = dm - (float)(g0 + 1) * step;
            float v0 = (g0 < GDIM)     ? __expf(coeff * d0 * d0) : 0.0f;
            float v1 = (g0 + 1 < GDIM) ? __expf(coeff * d1 * d1) : 0.0f;
            ap[jj] = pk2bf(v0, v1);
        }
        short8 af;
        __builtin_memcpy(&af, ap, 16);
        #pragma unroll
        for (int nt = 0; nt < 8; nt++) {
            short8 bfg = *(const short8*)&s_w1T[(nt * 16 + l15) * KW1 + ks * 32 + quad * 8];
            acc1[nt] = __builtin_amdgcn_mfma_f32_16x16x32_bf16(af, bfg, acc1[nt], 0, 0, 0);
        }
    }
    __syncthreads();   // all waves done reading s_w1T; s_t may alias it

    #pragma unroll
    for (int nt = 0; nt < 8; nt++) {
        #pragma unroll
        for (int r = 0; r < 4; r++) {
            int row = w * 16 + quad * 4 + r;
            s_t[row * KW2 + nt * 16 + l15] = f2bf(ssp(acc1[nt][r] + b1v[nt]));
        }
    }
    // no barrier: wave reads only rows it wrote

    floatx4 acc2[8];
    #pragma unroll
    for (int nt = 0; nt < 8; nt++) acc2[nt] = (floatx4){0.f, 0.f, 0.f, 0.f};
    #pragma unroll
    for (int ks = 0; ks < 4; ks++) {
        short8 af = *(const short8*)&s_t[(w * 16 + l15) * KW2 + ks * 32 + quad * 8];
        #pragma unroll
        for (int nt = 0; nt < 8; nt++) {
            short8 bfg = *(const short8*)&s_w2T[(nt * 16 + l15) * KW2 + ks * 32 + quad * 8];
            acc2[nt] = __builtin_amdgcn_mfma_f32_16x16x32_bf16(af, bfg, acc2[nt], 0, 0, 0);
        }
    }

    #pragma unroll
    for (int nt = 0; nt < 8; nt++) {
        #pragma unroll
        for (int r = 0; r < 4; r++) {
            int row = w * 16 + quad * 4 + r;
            float d = (float)(k0 + row) * hstep;
            float cut = 0.5f * (__cosf(d * pioc) + 1.0f);
            Tg[(size_t)(k0 + row) * 128 + nt * 16 + l15] = f2bf((acc2[nt][r] + b2v[nt]) * cut);
        }
    }
}

// ---------------------------------------------------------------------------
// Fully-fused SchNet: one block = one molecule, 512 threads = 8 waves.
// GEMM tile per wave: rows (w&1)*16, cols (w>>1)*32.
// Gather (proven shape): wave serially covers 4 atoms, lane = 2 channels,
// 8-deep unrolled edge batches; nearest-knot plain-bf16 table (1 uint load =
// 2 channels, no lerp); sentinel edge -> zero hx row kills loop tails.
// ---------------------------------------------------------------------------
__global__ __launch_bounds__(512, 4) void fused_schnet_kernel(
    const int* __restrict__ z, const float* __restrict__ emb,
    const int* __restrict__ rowptr, const unsigned int* __restrict__ meta,
    const unsigned short* __restrict__ Tt,
    const unsigned short* __restrict__ Wtall,
    const float* __restrict__ cf2_b, const float* __restrict__ lin_b,
    const float* __restrict__ out1_b, const float* __restrict__ out2_w,
    const float* __restrict__ out2_b,
    float* __restrict__ out)
{
    __shared__ float s_h[32 * STRH];                 // 16.9 KB fp32 node state
    __shared__ float s_hx[33 * 128];                 // 16.9 KB; row 32 = zeros
    __shared__ unsigned short s_agg[32 * STRA];      //  8.7 KB bf16
    __shared__ unsigned int s_meta[MAXEPM];          //  4.0 KB
    __shared__ float s_red;
    unsigned short* s_t = (unsigned short*)s_hx;     // [32][STRA] alias (8.7KB)

    const int tid  = threadIdx.x;
    const int lane = tid & 63;
    const int w    = tid >> 6;          // wave 0..7
    const int l15  = lane & 15;
    const int quad = lane >> 4;
    const int r16  = (w & 1) * 16;      // GEMM row tile
    const int c32  = (w >> 1) * 32;     // GEMM col tile
    const int B0   = blockIdx.x * 32;   // molecule base atom

    // init h; zero hx dummy row
    for (int i = tid; i < 32 * 128; i += 512) {
        int row = i >> 7, col = i & 127;
        s_h[row * STRH + col] = emb[(size_t)z[B0 + row] * 128 + col];
    }
    if (tid < 128) s_hx[32 * 128 + tid] = 0.0f;
    if (tid == 0) s_red = 0.0f;

    // stage edge metadata + sentinel (knot 0, zero row 32)
    const int ebase = rowptr[B0];
    const int nE    = rowptr[B0 + 32] - ebase;
    for (int i = tid; i < nE; i += 512) s_meta[i] = meta[ebase + i];
    if (tid == 0) s_meta[nE] = 32u;

    // local row pointers for this wave's 4 atoms (5 bounds in lanes 0..4)
    const int rp = rowptr[B0 + w * 4 + min(lane, 4)] - ebase;

    const unsigned short* WtO = Wtall + 9 * 16384;   // out1^T

    for (int l = 0; l < 3; l++) {
        const unsigned short* W1 = Wtall + (size_t)(l * 3 + 0) * 16384;
        const unsigned short* W2 = Wtall + (size_t)(l * 3 + 1) * 16384;
        const unsigned short* W3 = Wtall + (size_t)(l * 3 + 2) * 16384;
        const unsigned short* Ttl = Tt + (size_t)l * KTAB * 128;

        __syncthreads();   // h ready (also covers init/meta staging at l=0)

        // ---- GEMM1: hx = h @ cf1 (16x32 tile per wave) ----
        floatx4 acc[2];
        #pragma unroll
        for (int nt = 0; nt < 2; nt++) acc[nt] = (floatx4){0.f, 0.f, 0.f, 0.f};
        #pragma unroll
        for (int ks = 0; ks < 4; ks++) {
            const float* hp = &s_h[(r16 + l15) * STRH + ks * 32 + quad * 8];
            float4 xa = *(const float4*)hp;
            float4 xb = *(const float4*)(hp + 4);
            unsigned int ap[4];
            ap[0] = pk2bf(xa.x, xa.y); ap[1] = pk2bf(xa.z, xa.w);
            ap[2] = pk2bf(xb.x, xb.y); ap[3] = pk2bf(xb.z, xb.w);
            short8 af;
            __builtin_memcpy(&af, ap, 16);
            #pragma unroll
            for (int nt = 0; nt < 2; nt++) {
                short8 bfg = *(const short8*)&W1[(size_t)(c32 + nt * 16 + l15) * 128 + ks * 32 + quad * 8];
                acc[nt] = __builtin_amdgcn_mfma_f32_16x16x32_bf16(af, bfg, acc[nt], 0, 0, 0);
            }
        }
        #pragma unroll
        for (int nt = 0; nt < 2; nt++) {
            #pragma unroll
            for (int r = 0; r < 4; r++)
                s_hx[(r16 + quad * 4 + r) * 128 + c32 + nt * 16 + l15] = acc[nt][r];
        }

        __syncthreads();   // hx complete before gather reads

        // ---- gather: wave per 4 atoms, 2 channels/lane, nearest-knot ----
        for (int al = 0; al < 4; al++) {
            const int e0 = __shfl(rp, al);
            const int e1 = __shfl(rp, al + 1);
            float ax[8], ay[8];
            #pragma unroll
            for (int j = 0; j < 8; j++) { ax[j] = 0.f; ay[j] = 0.f; }
            for (int e = e0; e < e1; e += 8) {
                #pragma unroll
                for (int j = 0; j < 8; j++) {
                    int idx = (e + j < e1) ? (e + j) : nE;   // sentinel
                    unsigned int q = s_meta[idx];
                    int tl   = q & 63;
                    int knot = q >> 6;
                    unsigned int tp = *(const unsigned int*)&Ttl[((size_t)knot << 7) + 2 * lane];
                    float2 hv = *(const float2*)&s_hx[(tl << 7) + 2 * lane];
                    ax[j] = fmaf(hv.x, __uint_as_float(tp << 16), ax[j]);
                    ay[j] = fmaf(hv.y, __uint_as_float(tp & 0xffff0000u), ay[j]);
                }
            }
            float sx = ((ax[0] + ax[1]) + (ax[2] + ax[3])) + ((ax[4] + ax[5]) + (ax[6] + ax[7]));
            float sy = ((ay[0] + ay[1]) + (ay[2] + ay[3])) + ((ay[4] + ay[5]) + (ay[6] + ay[7]));
            *(unsigned int*)&s_agg[(w * 4 + al) * STRA + 2 * lane] = pk2bf(sx, sy);
        }

        __syncthreads();   // agg complete; hx reads done (s_t alias safe)

        // ---- GEMM2: t = ssp(agg @ cf2 + b) ----
        float bva[2], bvb[2];
        #pragma unroll
        for (int nt = 0; nt < 2; nt++) {
            bva[nt] = cf2_b[l * 128 + c32 + nt * 16 + l15];
            bvb[nt] = lin_b[l * 128 + c32 + nt * 16 + l15];
        }
        #pragma unroll
        for (int nt = 0; nt < 2; nt++) acc[nt] = (floatx4){0.f, 0.f, 0.f, 0.f};
        #pragma unroll
        for (int ks = 0; ks < 4; ks++) {
            short8 af = *(const short8*)&s_agg[(r16 + l15) * STRA + ks * 32 + quad * 8];
            #pragma unroll
            for (int nt = 0; nt < 2; nt++) {
                short8 bfg = *(const short8*)&W2[(size_t)(c32 + nt * 16 + l15) * 128 + ks * 32 + quad * 8];
                acc[nt] = __builtin_amdgcn_mfma_f32_16x16x32_bf16(af, bfg, acc[nt], 0, 0, 0);
            }
        }
        #pragma unroll
        for (int nt = 0; nt < 2; nt++) {
            #pragma unroll
            for (int r = 0; r < 4; r++) {
                int row = r16 + quad * 4 + r;
                s_t[row * STRA + c32 + nt * 16 + l15] = f2bf(ssp(acc[nt][r] + bva[nt]));
            }
        }

        __syncthreads();   // t complete (cross-wave cols needed by GEMM3)

        // ---- GEMM3: h += t @ lin + b ----
        #pragma unroll
        for (int nt = 0; nt < 2; nt++) acc[nt] = (floatx4){0.f, 0.f, 0.f, 0.f};
        #pragma unroll
        for (int ks = 0; ks < 4; ks++) {
            short8 af = *(const short8*)&s_t[(r16 + l15) * STRA + ks * 32 + quad * 8];
            #pragma unroll
            for (int nt = 0; nt < 2; nt++) {
                short8 bfg = *(const short8*)&W3[(size_t)(c32 + nt * 16 + l15) * 128 + ks * 32 + quad * 8];
                acc[nt] = __builtin_amdgcn_mfma_f32_16x16x32_bf16(af, bfg, acc[nt], 0, 0, 0);
            }
        }
        #pragma unroll
        for (int nt = 0; nt < 2; nt++) {
            #pragma unroll
            for (int r = 0; r < 4; r++) {
                int row = r16 + quad * 4 + r;
                s_h[row * STRH + c32 + nt * 16 + l15] += acc[nt][r] + bvb[nt];
            }
        }
        // loop-top __syncthreads covers h
    }

    __syncthreads();

    // ---- head: out = sum_a ssp(h@out1 + b1)@out2 + 32*b2 ----
    const int c16 = (w >> 1) * 16;   // out1: 64 cols = 4 col tiles x 2 row tiles
    floatx4 ha = (floatx4){0.f, 0.f, 0.f, 0.f};
    #pragma unroll
    for (int ks = 0; ks < 4; ks++) {
        const float* hp = &s_h[(r16 + l15) * STRH + ks * 32 + quad * 8];
        float4 xa = *(const float4*)hp;
        float4 xb = *(const float4*)(hp + 4);
        unsigned int ap[4];
        ap[0] = pk2bf(xa.x, xa.y); ap[1] = pk2bf(xa.z, xa.w);
        ap[2] = pk2bf(xb.x, xb.y); ap[3] = pk2bf(xb.z, xb.w);
        short8 af;
        __builtin_memcpy(&af, ap, 16);
        short8 bfg = *(const short8*)&WtO[(size_t)(c16 + l15) * 128 + ks * 32 + quad * 8];
        ha = __builtin_amdgcn_mfma_f32_16x16x32_bf16(af, bfg, ha, 0, 0, 0);
    }
    float part = 0.0f;
    {
        float b1o = out1_b[c16 + l15];
        float o2  = out2_w[c16 + l15];
        #pragma unroll
        for (int r = 0; r < 4; r++)
            part += ssp(ha[r] + b1o) * o2;
    }
    #pragma unroll
    for (int off = 32; off > 0; off >>= 1) part += __shfl_down(part, off);
    if (lane == 0) atomicAdd(&s_red, part);
    __syncthreads();
    if (tid == 0) out[blockIdx.x] = s_red + 32.0f * out2_b[0];
}

extern "C" void kernel_launch(void* const* d_in, const int* in_sizes, int n_in,
                              void* d_out, int out_size, void* d_ws, size_t ws_size,
                              hipStream_t stream)
{
    const int*   z      = (const int*)d_in[0];
    const float* pos    = (const float*)d_in[1];
    const int*   eidx   = (const int*)d_in[3];
    const float* emb    = (const float*)d_in[4];
    const float* mlp_w1 = (const float*)d_in[5];
    const float* mlp_b1 = (const float*)d_in[6];
    const float* mlp_w2 = (const float*)d_in[7];
    const float* mlp_b2 = (const float*)d_in[8];
    const float* cf1_w  = (const float*)d_in[9];
    const float* cf2_w  = (const float*)d_in[10];
    const float* cf2_b  = (const float*)d_in[11];
    const float* lin_w  = (const float*)d_in[12];
    const float* lin_b  = (const float*)d_in[13];
    const float* out1_w = (const float*)d_in[14];
    const float* out1_b = (const float*)d_in[15];
    const float* out2_w = (const float*)d_in[16];
    const float* out2_b = (const float*)d_in[17];
    const int E = in_sizes[3] / 2;

    // workspace carve-up (16B-aligned sections)
    char* p = (char*)d_ws;
    unsigned int* meta = (unsigned int*)p;        p += ((size_t)(E + 1) * 4 + 63) & ~63ULL;
    unsigned short* Tt = (unsigned short*)p;      p += (size_t)3 * KTAB * 128 * 2;
    int* rowptr = (int*)p;                        p += ((size_t)(NATOMS + 1) * 4 + 63) & ~63ULL;
    unsigned short* Wtall = (unsigned short*)p;   // 9*16384 + 64*128 ushorts

    const int EB = (E + NATOMS + 1 + 255) / 256;
    const int WB = (9 * 16384 + 64 * 128 + 255) / 256;
    const int TB = NTILE * 3;
    mega_setup_kernel<<<EB + WB + TB, 256, 0, stream>>>(
        pos, eidx, E, EB, rowptr, cf1_w, cf2_w, lin_w, out1_w, Wtall, meta,
        mlp_w1, mlp_b1, mlp_w2, mlp_b2, Tt);

    fused_schnet_kernel<<<NMOL, 512, 0, stream>>>(
        z, emb, rowptr, meta, Tt, Wtall,
        cf2_b, lin_b, out1_b, out2_w, out2_b, (float*)d_out);
}